// Round 5
// baseline (1193.010 us; speedup 1.0000x reference)
//
#include <hip/hip_runtime.h>

typedef unsigned short u16;
typedef __bf16 bf16x8 __attribute__((ext_vector_type(8)));
typedef float f32x4 __attribute__((ext_vector_type(4)));
typedef float f32x16 __attribute__((ext_vector_type(16)));

#define N_NODES 100000
#define N_EDGES 1600000
#define TM 64      // mlp rows per block
#define HP1 1032   // h1 LDS row stride (1024 + 8 pad) in bf16 (16B-aligned rows)
#define SCP2 36    // phase-C scratch row stride (32 + 4 pad) in bf16
#define WTP 68     // sage LDS weight row stride (64 + 4 pad) in f32

__device__ __forceinline__ u16 f2bf(float f) {
    unsigned int u = __float_as_uint(f);
    u = (u + 0x7FFFu + ((u >> 16) & 1u)) >> 16;   // RTN
    return (u16)u;
}

// ---------------- transpose + f32->bf16 convert: out[c][r] = in[r][c] ----------------
__global__ __launch_bounds__(256) void transpose_cvt(const float* __restrict__ in,
                                                     u16* __restrict__ out, int R, int C) {
    __shared__ float tile[32][33];
    int tx = threadIdx.x, ty = threadIdx.y;
    int cb = blockIdx.x * 32, rb = blockIdx.y * 32;
#pragma unroll
    for (int i = 0; i < 4; ++i) {
        int r = rb + ty + i * 8, c = cb + tx;
        tile[ty + i * 8][tx] = (r < R && c < C) ? in[(size_t)r * C + c] : 0.f;
    }
    __syncthreads();
#pragma unroll
    for (int i = 0; i < 4; ++i) {
        int c = cb + ty + i * 8, r = rb + tx;
        if (r < R && c < C) out[(size_t)c * R + r] = f2bf(tile[tx][ty + i * 8]);
    }
}

// ---------------- CSR build: histogram, scan, fill ----------------
__global__ __launch_bounds__(256) void hist_deg(const int* __restrict__ dst,
                                                int* __restrict__ deg, int E) {
    int i = blockIdx.x * 256 + threadIdx.x;
    int st = gridDim.x * 256;
    for (; i < E; i += st) atomicAdd(&deg[dst[i]], 1);
}

__global__ __launch_bounds__(1024) void scan_deg(const int* __restrict__ deg,
                                                 int* __restrict__ offs, int N) {
    __shared__ int wsum[17];
    __shared__ int run;
    const int tid = threadIdx.x;
    const int lane = tid & 63;
    const int w = tid >> 6;
    if (tid == 0) run = 0;
    __syncthreads();
    for (int base = 0; base < N; base += 1024) {
        int idx = base + tid;
        int v = (idx < N) ? deg[idx] : 0;
        int x = v;
#pragma unroll
        for (int d = 1; d < 64; d <<= 1) {
            int t = __shfl_up(x, d);
            if (lane >= d) x += t;
        }
        if (lane == 63) wsum[w + 1] = x;
        __syncthreads();
        if (tid == 0) {
            wsum[0] = 0;
            int s = 0;
#pragma unroll
            for (int i = 1; i <= 16; ++i) { s += wsum[i]; wsum[i] = s; }
        }
        __syncthreads();
        int excl = run + wsum[w] + x - v;
        if (idx < N) offs[idx] = excl;
        int tot = wsum[16];
        __syncthreads();
        if (tid == 0) run += tot;
    }
}

__global__ __launch_bounds__(256) void fill_csr(const int* __restrict__ src,
                                                const int* __restrict__ dst,
                                                int* __restrict__ offs,
                                                int* __restrict__ eidx, int E) {
    int i = blockIdx.x * 256 + threadIdx.x;
    int st = gridDim.x * 256;
    for (; i < E; i += st) {
        int pos = atomicAdd(&offs[dst[i]], 1);
        eidx[pos] = src[i];
    }
}

// ---------------- gather aggregation: 4 nodes/wave (quarter-waves), float4 lanes ----------------
__global__ __launch_bounds__(256) void agg_mean(const f32x4* __restrict__ x4,
                                                const int* __restrict__ offs,
                                                const int* __restrict__ deg,
                                                const int* __restrict__ eidx,
                                                f32x4* __restrict__ mean4, int N) {
    int lane = threadIdx.x & 63;
    int q = lane >> 4, l16 = lane & 15;
    int wid = (blockIdx.x * 256 + threadIdx.x) >> 6;
    int nw = (gridDim.x * 256) >> 6;
    for (int n0 = wid * 4; n0 < N; n0 += nw * 4) {
        int n = n0 + q;
        bool valid = n < N;
        int end = valid ? offs[n] : 0;   // inclusive end after fill_csr
        int d = valid ? deg[n] : 0;
        int i = end - d;
        f32x4 s = {0.f, 0.f, 0.f, 0.f};
        for (; i + 4 <= end; i += 4) {
            int e0 = eidx[i], e1 = eidx[i + 1], e2 = eidx[i + 2], e3 = eidx[i + 3];
            f32x4 v0 = x4[e0 * 16 + l16];
            f32x4 v1 = x4[e1 * 16 + l16];
            f32x4 v2 = x4[e2 * 16 + l16];
            f32x4 v3 = x4[e3 * 16 + l16];
            s = s + v0 + v1 + v2 + v3;
        }
        for (; i < end; ++i) s = s + x4[eidx[i] * 16 + l16];
        if (valid) {
            float inv = 1.0f / fmaxf((float)d, 1.0f);
            f32x4 r = {s.x * inv, s.y * inv, s.z * inv, s.w * inv};
            mean4[n * 16 + l16] = r;
        }
    }
}

// ---------------- SAGE: out = mean @ Wl + bl + xin @ Wr; LDS-transposed weights, 4 nodes/stream ----------------
template <int CO>
__global__ __launch_bounds__(256) void sage_gemm(const f32x4* __restrict__ mean4,
                                                 const f32x4* __restrict__ xin4,
                                                 const float* __restrict__ Wl,
                                                 const float* __restrict__ Wr,
                                                 const float* __restrict__ bl,
                                                 float* __restrict__ out,
                                                 float* __restrict__ ssum,
                                                 float* __restrict__ ssq, int N) {
    __shared__ float WlT[CO * WTP], WrT[CO * WTP];   // [c][k], padded stride
    __shared__ float rsum[4 * CO], rsq[4 * CO];
    for (int i = threadIdx.x; i < 64 * CO; i += 256) {
        int k = i / CO, c = i % CO;
        WlT[c * WTP + k] = Wl[i];
        WrT[c * WTP + k] = Wr[i];
    }
    __syncthreads();
    const int lane = threadIdx.x & 63;
    const int wv = threadIdx.x >> 6;
    constexpr int NPW = 64 / CO;
    const int c = lane % CO;
    const int sub = lane / CO;
    const int wid = (blockIdx.x * 256 + threadIdx.x) >> 6;
    const int nw = (gridDim.x * 256) >> 6;
    const int g = wid * NPW + sub;
    const int ng = nw * NPW;
    const float bias = bl[c];
    const f32x4* wlrow = (const f32x4*)(WlT + c * WTP);
    const f32x4* wrrow = (const f32x4*)(WrT + c * WTP);
    float lsum = 0.f, lsq = 0.f;
    for (int n0 = g * 4; n0 < N; n0 += ng * 4) {
        float am[4] = {0.f, 0.f, 0.f, 0.f}, ax[4] = {0.f, 0.f, 0.f, 0.f};
#pragma unroll 4
        for (int k4 = 0; k4 < 16; ++k4) {
            f32x4 wl = wlrow[k4];
            f32x4 wr = wrrow[k4];
#pragma unroll
            for (int b = 0; b < 4; ++b) {
                f32x4 pa = mean4[(size_t)(n0 + b) * 16 + k4];
                f32x4 px = xin4[(size_t)(n0 + b) * 16 + k4];
                am[b] += pa.x * wl.x + pa.y * wl.y + pa.z * wl.z + pa.w * wl.w;
                ax[b] += px.x * wr.x + px.y * wr.y + px.z * wr.z + px.w * wr.w;
            }
        }
#pragma unroll
        for (int b = 0; b < 4; ++b) {
            float v = am[b] + ax[b] + bias;
            out[(size_t)(n0 + b) * CO + c] = v;
            lsum += v; lsq += v * v;
        }
    }
    if (CO == 32) {
        lsum += __shfl_xor(lsum, 32);
        lsq  += __shfl_xor(lsq, 32);
    }
    if (sub == 0) { rsum[wv * CO + c] = lsum; rsq[wv * CO + c] = lsq; }
    __syncthreads();
    if (threadIdx.x < CO) {
        float s = rsum[threadIdx.x] + rsum[CO + threadIdx.x] +
                  rsum[2 * CO + threadIdx.x] + rsum[3 * CO + threadIdx.x];
        float q2 = rsq[threadIdx.x] + rsq[CO + threadIdx.x] +
                   rsq[2 * CO + threadIdx.x] + rsq[3 * CO + threadIdx.x];
        atomicAdd(&ssum[threadIdx.x], s);
        atomicAdd(&ssq[threadIdx.x], q2);
    }
}

// ---------------- BN (batch stats) + ReLU, in place; optional bf16 copy ----------------
template <int CO, int WRITE_BF>
__global__ __launch_bounds__(256) void bn_relu(float* __restrict__ data,
                                               const float* __restrict__ ssum,
                                               const float* __restrict__ ssq,
                                               const float* __restrict__ g,
                                               const float* __restrict__ be,
                                               u16* __restrict__ xb, int N) {
    const float invN = 1.0f / (float)N_NODES;
    int idx = blockIdx.x * 256 + threadIdx.x;
    int total = N * CO;
    int stride = gridDim.x * 256;
    for (; idx < total; idx += stride) {
        int c = idx & (CO - 1);
        float mu = ssum[c] * invN;
        float var = ssq[c] * invN - mu * mu;
        float sc = rsqrtf(var + 1e-5f) * g[c];
        float v = (data[idx] - mu) * sc + be[c];
        v = fmaxf(v, 0.f);
        data[idx] = v;
        if (WRITE_BF) xb[idx] = f2bf(v);
    }
}

// ---------------- fused MLP: TM=64, 16 waves, wave owns 64 cols; Phase B = 32x32x16 MFMA ----------------
__global__ __launch_bounds__(1024, 4) void mlp_fused(const u16* __restrict__ xt2b,   // [100032][32]
                                                     const u16* __restrict__ W1T,    // [1024][32]
                                                     const float* __restrict__ bm1,
                                                     const u16* __restrict__ W2T,    // [1024][1024]
                                                     const float* __restrict__ bm2,
                                                     const u16* __restrict__ W3T,    // [16][1024]
                                                     const float* __restrict__ bm3,
                                                     float* __restrict__ probs,
                                                     float* __restrict__ logitsO) {
    __shared__ __align__(16) u16 h1s[TM * HP1];        // 132096 B (reused as f32 reduce buf)
    __shared__ __align__(16) u16 scr[16 * 16 * SCP2];  // 18432 B per-wave phase-C scratch
    const int tid = threadIdx.x;
    const int w = tid >> 6;          // 0..15
    const int lane = tid & 63;
    const int l16 = lane & 15;
    const int q = lane >> 4;
    const int m32 = lane & 31;       // 32x32 row/col index
    const int h8 = (lane >> 5) * 8;  // 32x32 k-offset
    const int row0 = blockIdx.x * TM;
    const int nb0 = w * 64;

    // ---- B pipeline preload (t=0,1) — issued before Phase A to hide L2/L3 latency
    bf16x8 bp[2][2];
#pragma unroll
    for (int s = 0; s < 2; ++s)
#pragma unroll
        for (int j = 0; j < 2; ++j)
            bp[s][j] = *(const bf16x8*)(W2T + (size_t)(nb0 + j * 32 + m32) * 1024 + s * 16 + h8);

    // ---- Phase A: h1 rows [row0,row0+64) = relu(xt2 @ Wm1 + bm1) -> LDS (wave fills its 64 cols)
#pragma unroll
    for (int mt = 0; mt < 4; ++mt) {
        const int grow = row0 + mt * 16 + l16;               // < 100032 (1563*64)
        bf16x8 a = *(const bf16x8*)(xt2b + grow * 32 + q * 8);
#pragma unroll
        for (int nt = 0; nt < 4; ++nt) {
            const int n = nb0 + nt * 16 + l16;
            bf16x8 b = *(const bf16x8*)(W1T + n * 32 + q * 8);
            f32x4 c = {0.f, 0.f, 0.f, 0.f};
            c = __builtin_amdgcn_mfma_f32_16x16x32_bf16(a, b, c, 0, 0, 0);
            const float bias = bm1[n];
#pragma unroll
            for (int r = 0; r < 4; ++r)
                h1s[(mt * 16 + q * 4 + r) * HP1 + n] = f2bf(fmaxf(c[r] + bias, 0.f));
        }
    }
    __syncthreads();

    // ---- Phase B: 64 k-steps of 16; wave computes 2x2 32x32 tiles (64 rows x 64 cols)
    f32x16 acc[2][2];
#pragma unroll
    for (int i2 = 0; i2 < 2; ++i2)
#pragma unroll
        for (int j = 0; j < 2; ++j)
#pragma unroll
            for (int r = 0; r < 16; ++r) acc[i2][j][r] = 0.f;

#pragma unroll 4
    for (int t = 0; t < 64; ++t) {
        const int s = t & 1;
        const int k0 = t * 16;
        bf16x8 a0 = *(const bf16x8*)(h1s + (0 * 32 + m32) * HP1 + k0 + h8);
        bf16x8 a1 = *(const bf16x8*)(h1s + (1 * 32 + m32) * HP1 + k0 + h8);
        acc[0][0] = __builtin_amdgcn_mfma_f32_32x32x16_bf16(a0, bp[s][0], acc[0][0], 0, 0, 0);
        acc[1][0] = __builtin_amdgcn_mfma_f32_32x32x16_bf16(a1, bp[s][0], acc[1][0], 0, 0, 0);
        acc[0][1] = __builtin_amdgcn_mfma_f32_32x32x16_bf16(a0, bp[s][1], acc[0][1], 0, 0, 0);
        acc[1][1] = __builtin_amdgcn_mfma_f32_32x32x16_bf16(a1, bp[s][1], acc[1][1], 0, 0, 0);
        const int tn = (t + 2 < 64) ? t + 2 : t;   // tail reloads are dead
#pragma unroll
        for (int j = 0; j < 2; ++j)
            bp[s][j] = *(const bf16x8*)(W2T + (size_t)(nb0 + j * 32 + m32) * 1024 + tn * 16 + h8);
    }

    // ---- epilogue + Phase C: per 16x32 chunk -> scratch (A-layout) -> logits MFMA
    const float bias2[2] = { bm2[nb0 + m32], bm2[nb0 + 32 + m32] };
    f32x4 plog[4];
#pragma unroll
    for (int mt = 0; mt < 4; ++mt) plog[mt] = (f32x4){0.f, 0.f, 0.f, 0.f};
    u16* sw = scr + w * 16 * SCP2;

#pragma unroll
    for (int i2 = 0; i2 < 2; ++i2)
#pragma unroll
        for (int rh = 0; rh < 2; ++rh) {
            const int mt = i2 * 2 + rh;
#pragma unroll
            for (int j = 0; j < 2; ++j) {
#pragma unroll
                for (int rr = 0; rr < 8; ++rr) {
                    // 32x32 C-layout: row=(reg&3)+8*(reg>>2)+4*(lane>>5), col=lane&31
                    const int row16 = (rr & 3) + 8 * (rr >> 2) + 4 * (lane >> 5);
                    float v = acc[i2][j][rh * 8 + rr] + bias2[j];
                    sw[row16 * SCP2 + m32] = f2bf(fmaxf(v, 0.f));
                }
                bf16x8 a2 = *(const bf16x8*)(sw + l16 * SCP2 + q * 8);
                bf16x8 b3 = *(const bf16x8*)(W3T + l16 * 1024 + nb0 + j * 32 + q * 8);
                plog[mt] = __builtin_amdgcn_mfma_f32_16x16x32_bf16(a2, b3, plog[mt], 0, 0, 0);
            }
        }

    // ---- cross-wave logit reduction (reuse h1s as f32 buffer: 16*4*64*16B = 64 KB)
    __syncthreads();
    f32x4* red = (f32x4*)h1s;
#pragma unroll
    for (int mt = 0; mt < 4; ++mt) red[(w * 4 + mt) * 64 + lane] = plog[mt];
    __syncthreads();

    if (w < 4) {                                   // wave w finalizes m-tile w
        f32x4 tot = red[w * 64 + lane];
#pragma unroll
        for (int w2 = 1; w2 < 16; ++w2) tot = tot + red[(w2 * 4 + w) * 64 + lane];
        const float b3v = bm3[l16];
#pragma unroll
        for (int r = 0; r < 4; ++r) {
            float v = tot[r] + b3v;
            float m = v;
            m = fmaxf(m, __shfl_xor(m, 1));
            m = fmaxf(m, __shfl_xor(m, 2));
            m = fmaxf(m, __shfl_xor(m, 4));
            m = fmaxf(m, __shfl_xor(m, 8));
            float e = __expf(v - m);
            float s = e;
            s += __shfl_xor(s, 1);
            s += __shfl_xor(s, 2);
            s += __shfl_xor(s, 4);
            s += __shfl_xor(s, 8);
            const int R = row0 + w * 16 + q * 4 + r;
            if (R < N_NODES) {
                logitsO[R * 16 + l16] = v;
                probs[R * 16 + l16] = e / s;
            }
        }
    }
}

extern "C" void kernel_launch(void* const* d_in, const int* in_sizes, int n_in,
                              void* d_out, int out_size, void* d_ws, size_t ws_size,
                              hipStream_t stream) {
    const float* x   = (const float*)d_in[0];
    const int*   ei  = (const int*)d_in[1];
    const int*   src = ei;
    const int*   dst = ei + N_EDGES;
    const float* W1l = (const float*)d_in[2];
    const float* b1l = (const float*)d_in[3];
    const float* W1r = (const float*)d_in[4];
    const float* g1  = (const float*)d_in[5];
    const float* be1 = (const float*)d_in[6];
    const float* W2l = (const float*)d_in[7];
    const float* b2l = (const float*)d_in[8];
    const float* W2r = (const float*)d_in[9];
    const float* g2  = (const float*)d_in[10];
    const float* be2 = (const float*)d_in[11];
    const float* Wm1 = (const float*)d_in[12];
    const float* bm1 = (const float*)d_in[13];
    const float* Wm2 = (const float*)d_in[14];
    const float* bm2 = (const float*)d_in[15];
    const float* Wm3 = (const float*)d_in[16];
    const float* bm3 = (const float*)d_in[17];

    float* probs  = (float*)d_out;                 // [N,16]
    float* logits = probs + 1600000;               // [N,16]
    float* xt1    = probs + 3200000;               // [N,64]
    float* xt2    = probs + 9600000;               // [N,32]

    char* wsb    = (char*)d_ws;
    int*  deg    = (int*)(wsb);                    //   400,000 B
    float* stats = (float*)(wsb + 400000);         //       768 B
    int*  offs   = (int*)(wsb + 400768);           //   400,000 B
    int*  eidx   = (int*)(wsb + 800768);           // 6,400,000 B
    float* mean  = (float*)(wsb + 7200768);        // 25,600,000 B
    u16*  xt2b   = (u16*)(wsb + 32800768);         // 6,402,048 B ([100032][32])
    u16*  W1T    = (u16*)(wsb + 39202816);         //    65,536 B
    u16*  W2T    = (u16*)(wsb + 39268352);         // 2,097,152 B
    u16*  W3T    = (u16*)(wsb + 41365504);         //    32,768 B  (end: 41,398,272)
    float* sum1 = stats, *sq1 = stats + 64, *sum2 = stats + 128, *sq2 = stats + 160;

    // zero deg + stats; zero xt2b tail rows 100000..100031
    hipMemsetAsync(wsb, 0, 400768, stream);
    hipMemsetAsync(xt2b + 100000 * 32, 0, 32 * 32 * sizeof(u16), stream);

    // weight transposes (bf16)
    transpose_cvt<<<dim3(32, 1),  dim3(32, 8), 0, stream>>>(Wm1, W1T, 32, 1024);
    transpose_cvt<<<dim3(32, 32), dim3(32, 8), 0, stream>>>(Wm2, W2T, 1024, 1024);
    transpose_cvt<<<dim3(1, 32),  dim3(32, 8), 0, stream>>>(Wm3, W3T, 1024, 16);

    // ---- CSR build (once; reused by both layers)
    hist_deg<<<6250, 256, 0, stream>>>(dst, deg, N_EDGES);
    scan_deg<<<1, 1024, 0, stream>>>(deg, offs, N_NODES);
    fill_csr<<<6250, 256, 0, stream>>>(src, dst, offs, eidx, N_EDGES);

    // ---- layer 1
    agg_mean<<<6250, 256, 0, stream>>>((const f32x4*)x, offs, deg, eidx, (f32x4*)mean, N_NODES);
    sage_gemm<64><<<512, 256, 0, stream>>>((const f32x4*)mean, (const f32x4*)x,
                                           W1l, W1r, b1l, xt1, sum1, sq1, N_NODES);
    bn_relu<64, 0><<<4096, 256, 0, stream>>>(xt1, sum1, sq1, g1, be1, nullptr, N_NODES);

    // ---- layer 2
    agg_mean<<<6250, 256, 0, stream>>>((const f32x4*)xt1, offs, deg, eidx, (f32x4*)mean, N_NODES);
    sage_gemm<32><<<512, 256, 0, stream>>>((const f32x4*)mean, (const f32x4*)xt1,
                                           W2l, W2r, b2l, xt2, sum2, sq2, N_NODES);
    bn_relu<32, 1><<<2048, 256, 0, stream>>>(xt2, sum2, sq2, g2, be2, xt2b, N_NODES);

    // ---- fused MLP + softmax
    mlp_fused<<<1563, 1024, 0, stream>>>(xt2b, W1T, bm1, W2T, bm2, W3T, bm3, probs, logits);
}

// Round 6
// 922.582 us; speedup vs baseline: 1.2931x; 1.2931x over previous
//
#include <hip/hip_runtime.h>

typedef unsigned short u16;
typedef unsigned short u16x8 __attribute__((ext_vector_type(8)));
typedef __bf16 bf16x8 __attribute__((ext_vector_type(8)));
typedef float f32x4 __attribute__((ext_vector_type(4)));
typedef float f32x16 __attribute__((ext_vector_type(16)));

#define N_NODES 100000
#define N_EDGES 1600000
#define TM 64      // mlp rows per block
#define HP1 1032   // h1 LDS row stride (1024 + 8 pad) in bf16 (16B-aligned rows)
#define SCP2 36    // phase-C scratch row stride (32 + 4 pad) in bf16
#define WTP 68     // sage LDS weight row stride (64 + 4 pad) in f32

__device__ __forceinline__ u16 f2bf(float f) {
    unsigned int u = __float_as_uint(f);
    u = (u + 0x7FFFu + ((u >> 16) & 1u)) >> 16;   // RTN
    return (u16)u;
}

// ---------------- transpose + f32->bf16 convert: out[c][r] = in[r][c] ----------------
__global__ __launch_bounds__(256) void transpose_cvt(const float* __restrict__ in,
                                                     u16* __restrict__ out, int R, int C) {
    __shared__ float tile[32][33];
    int tx = threadIdx.x, ty = threadIdx.y;
    int cb = blockIdx.x * 32, rb = blockIdx.y * 32;
#pragma unroll
    for (int i = 0; i < 4; ++i) {
        int r = rb + ty + i * 8, c = cb + tx;
        tile[ty + i * 8][tx] = (r < R && c < C) ? in[(size_t)r * C + c] : 0.f;
    }
    __syncthreads();
#pragma unroll
    for (int i = 0; i < 4; ++i) {
        int c = cb + ty + i * 8, r = rb + tx;
        if (r < R && c < C) out[(size_t)c * R + r] = f2bf(tile[tx][ty + i * 8]);
    }
}

// ---------------- pack Wm2 [k=1024][n=1024] f32 -> per-(wave,t,j,lane) MFMA-fragment order, bf16 ----------------
// W2P chunk (w,t,j): 64 lanes x 16B contiguous; lane l holds Wm2[t*16+(l>>5)*8 + i][w*64+j*32+(l&31)]
__global__ __launch_bounds__(256) void pack_w2(const float* __restrict__ Wm2,
                                               u16* __restrict__ W2P) {
    int idx = blockIdx.x * 256 + threadIdx.x;   // 0 .. 131071, one thread per 16B chunk-slice
    int lane = idx & 63;
    int chunk = idx >> 6;           // w*128 + t*2 + j
    int j = chunk & 1;
    int t = (chunk >> 1) & 63;
    int w = chunk >> 7;             // 0..15
    int n = w * 64 + j * 32 + (lane & 31);
    int kbase = t * 16 + (lane >> 5) * 8;
    u16x8 tmp;
#pragma unroll
    for (int i = 0; i < 8; ++i) tmp[i] = f2bf(Wm2[(size_t)(kbase + i) * 1024 + n]);
    *(u16x8*)(W2P + (size_t)idx * 8) = tmp;
}

// ---------------- CSR build: histogram, scan, fill ----------------
__global__ __launch_bounds__(256) void hist_deg(const int* __restrict__ dst,
                                                int* __restrict__ deg, int E) {
    int i = blockIdx.x * 256 + threadIdx.x;
    int st = gridDim.x * 256;
    for (; i < E; i += st) atomicAdd(&deg[dst[i]], 1);
}

__global__ __launch_bounds__(1024) void scan_deg(const int* __restrict__ deg,
                                                 int* __restrict__ offs, int N) {
    __shared__ int wsum[17];
    __shared__ int run;
    const int tid = threadIdx.x;
    const int lane = tid & 63;
    const int w = tid >> 6;
    if (tid == 0) run = 0;
    __syncthreads();
    for (int base = 0; base < N; base += 1024) {
        int idx = base + tid;
        int v = (idx < N) ? deg[idx] : 0;
        int x = v;
#pragma unroll
        for (int d = 1; d < 64; d <<= 1) {
            int t = __shfl_up(x, d);
            if (lane >= d) x += t;
        }
        if (lane == 63) wsum[w + 1] = x;
        __syncthreads();
        if (tid == 0) {
            wsum[0] = 0;
            int s = 0;
#pragma unroll
            for (int i = 1; i <= 16; ++i) { s += wsum[i]; wsum[i] = s; }
        }
        __syncthreads();
        int excl = run + wsum[w] + x - v;
        if (idx < N) offs[idx] = excl;
        int tot = wsum[16];
        __syncthreads();
        if (tid == 0) run += tot;
    }
}

__global__ __launch_bounds__(256) void fill_csr(const int* __restrict__ src,
                                                const int* __restrict__ dst,
                                                int* __restrict__ offs,
                                                int* __restrict__ eidx, int E) {
    int i = blockIdx.x * 256 + threadIdx.x;
    int st = gridDim.x * 256;
    for (; i < E; i += st) {
        int pos = atomicAdd(&offs[dst[i]], 1);
        eidx[pos] = src[i];
    }
}

// ---------------- gather aggregation: 4 nodes/wave (quarter-waves), float4 lanes ----------------
__global__ __launch_bounds__(256) void agg_mean(const f32x4* __restrict__ x4,
                                                const int* __restrict__ offs,
                                                const int* __restrict__ deg,
                                                const int* __restrict__ eidx,
                                                f32x4* __restrict__ mean4, int N) {
    int lane = threadIdx.x & 63;
    int q = lane >> 4, l16 = lane & 15;
    int wid = (blockIdx.x * 256 + threadIdx.x) >> 6;
    int nw = (gridDim.x * 256) >> 6;
    for (int n0 = wid * 4; n0 < N; n0 += nw * 4) {
        int n = n0 + q;
        bool valid = n < N;
        int end = valid ? offs[n] : 0;   // inclusive end after fill_csr
        int d = valid ? deg[n] : 0;
        int i = end - d;
        f32x4 s = {0.f, 0.f, 0.f, 0.f};
        for (; i + 4 <= end; i += 4) {
            int e0 = eidx[i], e1 = eidx[i + 1], e2 = eidx[i + 2], e3 = eidx[i + 3];
            f32x4 v0 = x4[e0 * 16 + l16];
            f32x4 v1 = x4[e1 * 16 + l16];
            f32x4 v2 = x4[e2 * 16 + l16];
            f32x4 v3 = x4[e3 * 16 + l16];
            s = s + v0 + v1 + v2 + v3;
        }
        for (; i < end; ++i) s = s + x4[eidx[i] * 16 + l16];
        if (valid) {
            float inv = 1.0f / fmaxf((float)d, 1.0f);
            f32x4 r = {s.x * inv, s.y * inv, s.z * inv, s.w * inv};
            mean4[n * 16 + l16] = r;
        }
    }
}

// ---------------- SAGE: out = mean @ Wl + bl + xin @ Wr; LDS-transposed weights, 4 nodes/stream ----------------
template <int CO>
__global__ __launch_bounds__(256) void sage_gemm(const f32x4* __restrict__ mean4,
                                                 const f32x4* __restrict__ xin4,
                                                 const float* __restrict__ Wl,
                                                 const float* __restrict__ Wr,
                                                 const float* __restrict__ bl,
                                                 float* __restrict__ out,
                                                 float* __restrict__ ssum,
                                                 float* __restrict__ ssq, int N) {
    __shared__ float WlT[CO * WTP], WrT[CO * WTP];   // [c][k], padded stride
    __shared__ float rsum[4 * CO], rsq[4 * CO];
    for (int i = threadIdx.x; i < 64 * CO; i += 256) {
        int k = i / CO, c = i % CO;
        WlT[c * WTP + k] = Wl[i];
        WrT[c * WTP + k] = Wr[i];
    }
    __syncthreads();
    const int lane = threadIdx.x & 63;
    const int wv = threadIdx.x >> 6;
    constexpr int NPW = 64 / CO;
    const int c = lane % CO;
    const int sub = lane / CO;
    const int wid = (blockIdx.x * 256 + threadIdx.x) >> 6;
    const int nw = (gridDim.x * 256) >> 6;
    const int g = wid * NPW + sub;
    const int ng = nw * NPW;
    const float bias = bl[c];
    const f32x4* wlrow = (const f32x4*)(WlT + c * WTP);
    const f32x4* wrrow = (const f32x4*)(WrT + c * WTP);
    float lsum = 0.f, lsq = 0.f;
    for (int n0 = g * 4; n0 < N; n0 += ng * 4) {
        float am[4] = {0.f, 0.f, 0.f, 0.f}, ax[4] = {0.f, 0.f, 0.f, 0.f};
#pragma unroll 4
        for (int k4 = 0; k4 < 16; ++k4) {
            f32x4 wl = wlrow[k4];
            f32x4 wr = wrrow[k4];
#pragma unroll
            for (int b = 0; b < 4; ++b) {
                f32x4 pa = mean4[(size_t)(n0 + b) * 16 + k4];
                f32x4 px = xin4[(size_t)(n0 + b) * 16 + k4];
                am[b] += pa.x * wl.x + pa.y * wl.y + pa.z * wl.z + pa.w * wl.w;
                ax[b] += px.x * wr.x + px.y * wr.y + px.z * wr.z + px.w * wr.w;
            }
        }
#pragma unroll
        for (int b = 0; b < 4; ++b) {
            float v = am[b] + ax[b] + bias;
            out[(size_t)(n0 + b) * CO + c] = v;
            lsum += v; lsq += v * v;
        }
    }
    if (CO == 32) {
        lsum += __shfl_xor(lsum, 32);
        lsq  += __shfl_xor(lsq, 32);
    }
    if (sub == 0) { rsum[wv * CO + c] = lsum; rsq[wv * CO + c] = lsq; }
    __syncthreads();
    if (threadIdx.x < CO) {
        float s = rsum[threadIdx.x] + rsum[CO + threadIdx.x] +
                  rsum[2 * CO + threadIdx.x] + rsum[3 * CO + threadIdx.x];
        float q2 = rsq[threadIdx.x] + rsq[CO + threadIdx.x] +
                   rsq[2 * CO + threadIdx.x] + rsq[3 * CO + threadIdx.x];
        atomicAdd(&ssum[threadIdx.x], s);
        atomicAdd(&ssq[threadIdx.x], q2);
    }
}

// ---------------- BN (batch stats) + ReLU, in place; optional bf16 copy ----------------
template <int CO, int WRITE_BF>
__global__ __launch_bounds__(256) void bn_relu(float* __restrict__ data,
                                               const float* __restrict__ ssum,
                                               const float* __restrict__ ssq,
                                               const float* __restrict__ g,
                                               const float* __restrict__ be,
                                               u16* __restrict__ xb, int N) {
    const float invN = 1.0f / (float)N_NODES;
    int idx = blockIdx.x * 256 + threadIdx.x;
    int total = N * CO;
    int stride = gridDim.x * 256;
    for (; idx < total; idx += stride) {
        int c = idx & (CO - 1);
        float mu = ssum[c] * invN;
        float var = ssq[c] * invN - mu * mu;
        float sc = rsqrtf(var + 1e-5f) * g[c];
        float v = (data[idx] - mu) * sc + be[c];
        v = fmaxf(v, 0.f);
        data[idx] = v;
        if (WRITE_BF) xb[idx] = f2bf(v);
    }
}

// ---------------- fused MLP: TM=64, 16 waves, wave owns 64 cols; Phase B = 32x32x16 MFMA,
// ---------------- B from fragment-packed W2P (coalesced 1KB/instr streaming loads) ----------------
__global__ __launch_bounds__(1024, 4) void mlp_fused(const u16* __restrict__ xt2b,   // [100032][32]
                                                     const u16* __restrict__ W1T,    // [1024][32]
                                                     const float* __restrict__ bm1,
                                                     const u16* __restrict__ W2P,    // packed, 2 MB
                                                     const float* __restrict__ bm2,
                                                     const u16* __restrict__ W3T,    // [16][1024]
                                                     const float* __restrict__ bm3,
                                                     float* __restrict__ probs,
                                                     float* __restrict__ logitsO) {
    __shared__ __align__(16) u16 h1s[TM * HP1];        // 132096 B (reused as f32 reduce buf)
    __shared__ __align__(16) u16 scr[16 * 16 * SCP2];  // 18432 B per-wave phase-C scratch
    const int tid = threadIdx.x;
    const int w = tid >> 6;          // 0..15
    const int lane = tid & 63;
    const int l16 = lane & 15;
    const int q = lane >> 4;
    const int m32 = lane & 31;       // 32x32 row/col index
    const int h8 = (lane >> 5) * 8;  // 32x32 k-offset
    const int row0 = blockIdx.x * TM;
    const int nb0 = w * 64;

    // per-wave packed-B stream base: chunk (t,j) at wq + (t*2+j)*512
    const u16* wq = W2P + (size_t)w * 128 * 512 + (size_t)lane * 8;

    // ---- B pipeline preload (t=0,1) — issued before Phase A to hide latency
    bf16x8 bp[2][2];
#pragma unroll
    for (int s = 0; s < 2; ++s)
#pragma unroll
        for (int j = 0; j < 2; ++j)
            bp[s][j] = *(const bf16x8*)(wq + (s * 2 + j) * 512);

    // ---- Phase A: h1 rows [row0,row0+64) = relu(xt2 @ Wm1 + bm1) -> LDS (wave fills its 64 cols)
#pragma unroll
    for (int mt = 0; mt < 4; ++mt) {
        const int grow = row0 + mt * 16 + l16;               // < 100032 (1563*64)
        bf16x8 a = *(const bf16x8*)(xt2b + grow * 32 + q * 8);
#pragma unroll
        for (int nt = 0; nt < 4; ++nt) {
            const int n = nb0 + nt * 16 + l16;
            bf16x8 b = *(const bf16x8*)(W1T + n * 32 + q * 8);
            f32x4 c = {0.f, 0.f, 0.f, 0.f};
            c = __builtin_amdgcn_mfma_f32_16x16x32_bf16(a, b, c, 0, 0, 0);
            const float bias = bm1[n];
#pragma unroll
            for (int r = 0; r < 4; ++r)
                h1s[(mt * 16 + q * 4 + r) * HP1 + n] = f2bf(fmaxf(c[r] + bias, 0.f));
        }
    }
    __syncthreads();

    // ---- Phase B: 64 k-steps of 16; wave computes 2x2 32x32 tiles (64 rows x 64 cols)
    f32x16 acc[2][2];
#pragma unroll
    for (int i2 = 0; i2 < 2; ++i2)
#pragma unroll
        for (int j = 0; j < 2; ++j)
#pragma unroll
            for (int r = 0; r < 16; ++r) acc[i2][j][r] = 0.f;

#pragma unroll 4
    for (int t = 0; t < 64; ++t) {
        const int s = t & 1;
        const int k0 = t * 16;
        bf16x8 a0 = *(const bf16x8*)(h1s + (0 * 32 + m32) * HP1 + k0 + h8);
        bf16x8 a1 = *(const bf16x8*)(h1s + (1 * 32 + m32) * HP1 + k0 + h8);
        acc[0][0] = __builtin_amdgcn_mfma_f32_32x32x16_bf16(a0, bp[s][0], acc[0][0], 0, 0, 0);
        acc[1][0] = __builtin_amdgcn_mfma_f32_32x32x16_bf16(a1, bp[s][0], acc[1][0], 0, 0, 0);
        acc[0][1] = __builtin_amdgcn_mfma_f32_32x32x16_bf16(a0, bp[s][1], acc[0][1], 0, 0, 0);
        acc[1][1] = __builtin_amdgcn_mfma_f32_32x32x16_bf16(a1, bp[s][1], acc[1][1], 0, 0, 0);
        const int tn = (t + 2 < 64) ? t + 2 : t;   // tail reloads are dead
        bp[s][0] = *(const bf16x8*)(wq + (tn * 2 + 0) * 512);
        bp[s][1] = *(const bf16x8*)(wq + (tn * 2 + 1) * 512);
    }

    // ---- epilogue + Phase C: per 16x32 chunk -> scratch (A-layout) -> logits MFMA
    const float bias2[2] = { bm2[nb0 + m32], bm2[nb0 + 32 + m32] };
    f32x4 plog[4];
#pragma unroll
    for (int mt = 0; mt < 4; ++mt) plog[mt] = (f32x4){0.f, 0.f, 0.f, 0.f};
    u16* sw = scr + w * 16 * SCP2;

#pragma unroll
    for (int i2 = 0; i2 < 2; ++i2)
#pragma unroll
        for (int rh = 0; rh < 2; ++rh) {
            const int mt = i2 * 2 + rh;
#pragma unroll
            for (int j = 0; j < 2; ++j) {
#pragma unroll
                for (int rr = 0; rr < 8; ++rr) {
                    // 32x32 C-layout: row=(reg&3)+8*(reg>>2)+4*(lane>>5), col=lane&31
                    const int row16 = (rr & 3) + 8 * (rr >> 2) + 4 * (lane >> 5);
                    float v = acc[i2][j][rh * 8 + rr] + bias2[j];
                    sw[row16 * SCP2 + m32] = f2bf(fmaxf(v, 0.f));
                }
                bf16x8 a2 = *(const bf16x8*)(sw + l16 * SCP2 + q * 8);
                bf16x8 b3 = *(const bf16x8*)(W3T + l16 * 1024 + nb0 + j * 32 + q * 8);
                plog[mt] = __builtin_amdgcn_mfma_f32_16x16x32_bf16(a2, b3, plog[mt], 0, 0, 0);
            }
        }

    // ---- cross-wave logit reduction (reuse h1s as f32 buffer: 16*4*64*16B = 64 KB)
    __syncthreads();
    f32x4* red = (f32x4*)h1s;
#pragma unroll
    for (int mt = 0; mt < 4; ++mt) red[(w * 4 + mt) * 64 + lane] = plog[mt];
    __syncthreads();

    if (w < 4) {                                   // wave w finalizes m-tile w
        f32x4 tot = red[w * 64 + lane];
#pragma unroll
        for (int w2 = 1; w2 < 16; ++w2) tot = tot + red[(w2 * 4 + w) * 64 + lane];
        const float b3v = bm3[l16];
#pragma unroll
        for (int r = 0; r < 4; ++r) {
            float v = tot[r] + b3v;
            float m = v;
            m = fmaxf(m, __shfl_xor(m, 1));
            m = fmaxf(m, __shfl_xor(m, 2));
            m = fmaxf(m, __shfl_xor(m, 4));
            m = fmaxf(m, __shfl_xor(m, 8));
            float e = __expf(v - m);
            float s = e;
            s += __shfl_xor(s, 1);
            s += __shfl_xor(s, 2);
            s += __shfl_xor(s, 4);
            s += __shfl_xor(s, 8);
            const int R = row0 + w * 16 + q * 4 + r;
            if (R < N_NODES) {
                logitsO[R * 16 + l16] = v;
                probs[R * 16 + l16] = e / s;
            }
        }
    }
}

extern "C" void kernel_launch(void* const* d_in, const int* in_sizes, int n_in,
                              void* d_out, int out_size, void* d_ws, size_t ws_size,
                              hipStream_t stream) {
    const float* x   = (const float*)d_in[0];
    const int*   ei  = (const int*)d_in[1];
    const int*   src = ei;
    const int*   dst = ei + N_EDGES;
    const float* W1l = (const float*)d_in[2];
    const float* b1l = (const float*)d_in[3];
    const float* W1r = (const float*)d_in[4];
    const float* g1  = (const float*)d_in[5];
    const float* be1 = (const float*)d_in[6];
    const float* W2l = (const float*)d_in[7];
    const float* b2l = (const float*)d_in[8];
    const float* W2r = (const float*)d_in[9];
    const float* g2  = (const float*)d_in[10];
    const float* be2 = (const float*)d_in[11];
    const float* Wm1 = (const float*)d_in[12];
    const float* bm1 = (const float*)d_in[13];
    const float* Wm2 = (const float*)d_in[14];
    const float* bm2 = (const float*)d_in[15];
    const float* Wm3 = (const float*)d_in[16];
    const float* bm3 = (const float*)d_in[17];

    float* probs  = (float*)d_out;                 // [N,16]
    float* logits = probs + 1600000;               // [N,16]
    float* xt1    = probs + 3200000;               // [N,64]
    float* xt2    = probs + 9600000;               // [N,32]

    char* wsb    = (char*)d_ws;
    int*  deg    = (int*)(wsb);                    //   400,000 B
    float* stats = (float*)(wsb + 400000);         //       768 B
    int*  offs   = (int*)(wsb + 400768);           //   400,000 B
    int*  eidx   = (int*)(wsb + 800768);           // 6,400,000 B
    float* mean  = (float*)(wsb + 7200768);        // 25,600,000 B
    u16*  xt2b   = (u16*)(wsb + 32800768);         // 6,402,048 B ([100032][32])
    u16*  W1T    = (u16*)(wsb + 39202816);         //    65,536 B
    u16*  W2P    = (u16*)(wsb + 39268352);         // 2,097,152 B (fragment-packed Wm2)
    u16*  W3T    = (u16*)(wsb + 41365504);         //    32,768 B  (end: 41,398,272)
    float* sum1 = stats, *sq1 = stats + 64, *sum2 = stats + 128, *sq2 = stats + 160;

    // zero deg + stats; zero xt2b tail rows 100000..100031
    hipMemsetAsync(wsb, 0, 400768, stream);
    hipMemsetAsync(xt2b + 100000 * 32, 0, 32 * 32 * sizeof(u16), stream);

    // weight transforms (bf16)
    transpose_cvt<<<dim3(32, 1),  dim3(32, 8), 0, stream>>>(Wm1, W1T, 32, 1024);
    pack_w2<<<512, 256, 0, stream>>>(Wm2, W2P);
    transpose_cvt<<<dim3(1, 32),  dim3(32, 8), 0, stream>>>(Wm3, W3T, 1024, 16);

    // ---- CSR build (once; reused by both layers)
    hist_deg<<<6250, 256, 0, stream>>>(dst, deg, N_EDGES);
    scan_deg<<<1, 1024, 0, stream>>>(deg, offs, N_NODES);
    fill_csr<<<6250, 256, 0, stream>>>(src, dst, offs, eidx, N_EDGES);

    // ---- layer 1
    agg_mean<<<6250, 256, 0, stream>>>((const f32x4*)x, offs, deg, eidx, (f32x4*)mean, N_NODES);
    sage_gemm<64><<<512, 256, 0, stream>>>((const f32x4*)mean, (const f32x4*)x,
                                           W1l, W1r, b1l, xt1, sum1, sq1, N_NODES);
    bn_relu<64, 0><<<4096, 256, 0, stream>>>(xt1, sum1, sq1, g1, be1, nullptr, N_NODES);

    // ---- layer 2
    agg_mean<<<6250, 256, 0, stream>>>((const f32x4*)xt1, offs, deg, eidx, (f32x4*)mean, N_NODES);
    sage_gemm<32><<<512, 256, 0, stream>>>((const f32x4*)mean, (const f32x4*)xt1,
                                           W2l, W2r, b2l, xt2, sum2, sq2, N_NODES);
    bn_relu<32, 1><<<2048, 256, 0, stream>>>(xt2, sum2, sq2, g2, be2, xt2b, N_NODES);

    // ---- fused MLP + softmax
    mlp_fused<<<1563, 1024, 0, stream>>>(xt2b, W1T, bm1, W2P, bm2, W3T, bm3, probs, logits);
}

// Round 7
// 847.420 us; speedup vs baseline: 1.4078x; 1.0887x over previous
//
#include <hip/hip_runtime.h>

typedef unsigned short u16;
typedef unsigned short u16x8 __attribute__((ext_vector_type(8)));
typedef __bf16 bf16x8 __attribute__((ext_vector_type(8)));
typedef float f32x4 __attribute__((ext_vector_type(4)));
typedef float f32x16 __attribute__((ext_vector_type(16)));

#define N_NODES 100000
#define N_EDGES 1600000
#define TM 64      // mlp rows per block
#define HP1 1032   // h1 LDS row stride (1024 + 8 pad) in bf16 (16B-aligned rows)
#define SCP2 36    // phase-C scratch row stride (32 + 4 pad) in bf16
#define WTP 68     // sage LDS weight row stride (64 + 4 pad) in f32

__device__ __forceinline__ u16 f2bf(float f) {
    unsigned int u = __float_as_uint(f);
    u = (u + 0x7FFFu + ((u >> 16) & 1u)) >> 16;   // RTN
    return (u16)u;
}

// ---------------- transpose + f32->bf16 convert: out[c][r] = in[r][c] ----------------
__global__ __launch_bounds__(256) void transpose_cvt(const float* __restrict__ in,
                                                     u16* __restrict__ out, int R, int C) {
    __shared__ float tile[32][33];
    int tx = threadIdx.x, ty = threadIdx.y;
    int cb = blockIdx.x * 32, rb = blockIdx.y * 32;
#pragma unroll
    for (int i = 0; i < 4; ++i) {
        int r = rb + ty + i * 8, c = cb + tx;
        tile[ty + i * 8][tx] = (r < R && c < C) ? in[(size_t)r * C + c] : 0.f;
    }
    __syncthreads();
#pragma unroll
    for (int i = 0; i < 4; ++i) {
        int c = cb + ty + i * 8, r = rb + tx;
        if (r < R && c < C) out[(size_t)c * R + r] = f2bf(tile[tx][ty + i * 8]);
    }
}

// ---------------- pack Wm2 [k=1024][n=1024] f32 -> per-(wave,t,j,lane) MFMA-fragment order, bf16 ----------------
__global__ __launch_bounds__(256) void pack_w2(const float* __restrict__ Wm2,
                                               u16* __restrict__ W2P) {
    int idx = blockIdx.x * 256 + threadIdx.x;   // 0 .. 131071
    int lane = idx & 63;
    int chunk = idx >> 6;           // w*128 + t*2 + j
    int j = chunk & 1;
    int t = (chunk >> 1) & 63;
    int w = chunk >> 7;             // 0..15
    int n = w * 64 + j * 32 + (lane & 31);
    int kbase = t * 16 + (lane >> 5) * 8;
    u16x8 tmp;
#pragma unroll
    for (int i = 0; i < 8; ++i) tmp[i] = f2bf(Wm2[(size_t)(kbase + i) * 1024 + n]);
    *(u16x8*)(W2P + (size_t)idx * 8) = tmp;
}

// ---------------- CSR build: histogram, multi-block scan, fill ----------------
__global__ __launch_bounds__(256) void hist_deg(const int* __restrict__ dst,
                                                int* __restrict__ deg, int E) {
    int i = blockIdx.x * 256 + threadIdx.x;
    int st = gridDim.x * 256;
    for (; i < E; i += st) atomicAdd(&deg[dst[i]], 1);
}

// per-block exclusive scan (1024 elems/block) + block totals
__global__ __launch_bounds__(1024) void scan_blk(const int* __restrict__ deg,
                                                 int* __restrict__ offs,
                                                 int* __restrict__ bsum, int N) {
    __shared__ int wsum[17];
    const int tid = threadIdx.x;
    const int lane = tid & 63;
    const int w = tid >> 6;
    const int idx = blockIdx.x * 1024 + tid;
    int v = (idx < N) ? deg[idx] : 0;
    int x = v;
#pragma unroll
    for (int d = 1; d < 64; d <<= 1) {
        int t = __shfl_up(x, d);
        if (lane >= d) x += t;
    }
    if (lane == 63) wsum[w + 1] = x;
    __syncthreads();
    if (tid == 0) {
        wsum[0] = 0;
        int s = 0;
#pragma unroll
        for (int i = 1; i <= 16; ++i) { s += wsum[i]; wsum[i] = s; }
        bsum[blockIdx.x] = s;
    }
    __syncthreads();
    if (idx < N) offs[idx] = wsum[w] + x - v;
}

// single-wave exclusive scan of block totals (nb <= a few hundred)
__global__ __launch_bounds__(64) void scan_top(int* __restrict__ bsum, int nb) {
    const int lane = threadIdx.x;
    int run = 0;
    for (int base = 0; base < nb; base += 64) {
        int idx = base + lane;
        int v = (idx < nb) ? bsum[idx] : 0;
        int x = v;
#pragma unroll
        for (int d = 1; d < 64; d <<= 1) {
            int t = __shfl_up(x, d);
            if (lane >= d) x += t;
        }
        if (idx < nb) bsum[idx] = run + x - v;
        run += __shfl(x, 63);
    }
}

__global__ __launch_bounds__(1024) void scan_add(int* __restrict__ offs,
                                                 const int* __restrict__ bsum, int N) {
    int idx = blockIdx.x * 1024 + threadIdx.x;
    if (idx < N) offs[idx] += bsum[blockIdx.x];
}

// fill: mutates offs[n] exclusive-start -> inclusive-end; eidx gets src ids
__global__ __launch_bounds__(256) void fill_csr(const int* __restrict__ src,
                                                const int* __restrict__ dst,
                                                int* __restrict__ offs,
                                                int* __restrict__ eidx, int E) {
    int i = blockIdx.x * 256 + threadIdx.x;
    int st = gridDim.x * 256;
    for (; i < E; i += st) {
        int pos = atomicAdd(&offs[dst[i]], 1);
        eidx[pos] = src[i];
    }
}

// ---------------- gather aggregation: 4 nodes/wave (quarter-waves), float4 lanes, 8-deep ----------------
__global__ __launch_bounds__(256) void agg_mean(const f32x4* __restrict__ x4,
                                                const int* __restrict__ offs,
                                                const int* __restrict__ deg,
                                                const int* __restrict__ eidx,
                                                f32x4* __restrict__ mean4, int N) {
    int lane = threadIdx.x & 63;
    int q = lane >> 4, l16 = lane & 15;
    int wid = (blockIdx.x * 256 + threadIdx.x) >> 6;
    int nw = (gridDim.x * 256) >> 6;
    for (int n0 = wid * 4; n0 < N; n0 += nw * 4) {
        int n = n0 + q;
        bool valid = n < N;
        int end = valid ? offs[n] : 0;   // inclusive end after fill_csr
        int d = valid ? deg[n] : 0;
        int i = end - d;
        f32x4 s = {0.f, 0.f, 0.f, 0.f};
        for (; i + 8 <= end; i += 8) {
            int e0 = eidx[i],     e1 = eidx[i + 1], e2 = eidx[i + 2], e3 = eidx[i + 3];
            int e4 = eidx[i + 4], e5 = eidx[i + 5], e6 = eidx[i + 6], e7 = eidx[i + 7];
            f32x4 v0 = x4[e0 * 16 + l16];
            f32x4 v1 = x4[e1 * 16 + l16];
            f32x4 v2 = x4[e2 * 16 + l16];
            f32x4 v3 = x4[e3 * 16 + l16];
            f32x4 v4 = x4[e4 * 16 + l16];
            f32x4 v5 = x4[e5 * 16 + l16];
            f32x4 v6 = x4[e6 * 16 + l16];
            f32x4 v7 = x4[e7 * 16 + l16];
            s = s + ((v0 + v1) + (v2 + v3)) + ((v4 + v5) + (v6 + v7));
        }
        for (; i + 2 <= end; i += 2) {
            int e0 = eidx[i], e1 = eidx[i + 1];
            s = s + x4[e0 * 16 + l16] + x4[e1 * 16 + l16];
        }
        if (i < end) s = s + x4[eidx[i] * 16 + l16];
        if (valid) {
            float inv = 1.0f / fmaxf((float)d, 1.0f);
            f32x4 r = {s.x * inv, s.y * inv, s.z * inv, s.w * inv};
            mean4[n * 16 + l16] = r;
        }
    }
}

// ---------------- SAGE: out = mean @ Wl + bl + xin @ Wr; LDS-transposed weights, 4 nodes/stream ----------------
template <int CO>
__global__ __launch_bounds__(256) void sage_gemm(const f32x4* __restrict__ mean4,
                                                 const f32x4* __restrict__ xin4,
                                                 const float* __restrict__ Wl,
                                                 const float* __restrict__ Wr,
                                                 const float* __restrict__ bl,
                                                 float* __restrict__ out,
                                                 float* __restrict__ ssum,
                                                 float* __restrict__ ssq, int N) {
    __shared__ float WlT[CO * WTP], WrT[CO * WTP];   // [c][k], padded stride
    __shared__ float rsum[4 * CO], rsq[4 * CO];
    for (int i = threadIdx.x; i < 64 * CO; i += 256) {
        int k = i / CO, c = i % CO;
        WlT[c * WTP + k] = Wl[i];
        WrT[c * WTP + k] = Wr[i];
    }
    __syncthreads();
    const int lane = threadIdx.x & 63;
    const int wv = threadIdx.x >> 6;
    constexpr int NPW = 64 / CO;
    const int c = lane % CO;
    const int sub = lane / CO;
    const int wid = (blockIdx.x * 256 + threadIdx.x) >> 6;
    const int nw = (gridDim.x * 256) >> 6;
    const int g = wid * NPW + sub;
    const int ng = nw * NPW;
    const float bias = bl[c];
    const f32x4* wlrow = (const f32x4*)(WlT + c * WTP);
    const f32x4* wrrow = (const f32x4*)(WrT + c * WTP);
    float lsum = 0.f, lsq = 0.f;
    for (int n0 = g * 4; n0 < N; n0 += ng * 4) {
        float am[4] = {0.f, 0.f, 0.f, 0.f}, ax[4] = {0.f, 0.f, 0.f, 0.f};
#pragma unroll 4
        for (int k4 = 0; k4 < 16; ++k4) {
            f32x4 wl = wlrow[k4];
            f32x4 wr = wrrow[k4];
#pragma unroll
            for (int b = 0; b < 4; ++b) {
                f32x4 pa = mean4[(size_t)(n0 + b) * 16 + k4];
                f32x4 px = xin4[(size_t)(n0 + b) * 16 + k4];
                am[b] += pa.x * wl.x + pa.y * wl.y + pa.z * wl.z + pa.w * wl.w;
                ax[b] += px.x * wr.x + px.y * wr.y + px.z * wr.z + px.w * wr.w;
            }
        }
#pragma unroll
        for (int b = 0; b < 4; ++b) {
            float v = am[b] + ax[b] + bias;
            out[(size_t)(n0 + b) * CO + c] = v;
            lsum += v; lsq += v * v;
        }
    }
    if (CO == 32) {
        lsum += __shfl_xor(lsum, 32);
        lsq  += __shfl_xor(lsq, 32);
    }
    if (sub == 0) { rsum[wv * CO + c] = lsum; rsq[wv * CO + c] = lsq; }
    __syncthreads();
    if (threadIdx.x < CO) {
        float s = rsum[threadIdx.x] + rsum[CO + threadIdx.x] +
                  rsum[2 * CO + threadIdx.x] + rsum[3 * CO + threadIdx.x];
        float q2 = rsq[threadIdx.x] + rsq[CO + threadIdx.x] +
                   rsq[2 * CO + threadIdx.x] + rsq[3 * CO + threadIdx.x];
        atomicAdd(&ssum[threadIdx.x], s);
        atomicAdd(&ssq[threadIdx.x], q2);
    }
}

// ---------------- BN (batch stats) + ReLU, in place; optional bf16 copy ----------------
template <int CO, int WRITE_BF>
__global__ __launch_bounds__(256) void bn_relu(float* __restrict__ data,
                                               const float* __restrict__ ssum,
                                               const float* __restrict__ ssq,
                                               const float* __restrict__ g,
                                               const float* __restrict__ be,
                                               u16* __restrict__ xb, int N) {
    const float invN = 1.0f / (float)N_NODES;
    int idx = blockIdx.x * 256 + threadIdx.x;
    int total = N * CO;
    int stride = gridDim.x * 256;
    for (; idx < total; idx += stride) {
        int c = idx & (CO - 1);
        float mu = ssum[c] * invN;
        float var = ssq[c] * invN - mu * mu;
        float sc = rsqrtf(var + 1e-5f) * g[c];
        float v = (data[idx] - mu) * sc + be[c];
        v = fmaxf(v, 0.f);
        data[idx] = v;
        if (WRITE_BF) xb[idx] = f2bf(v);
    }
}

// ---------------- fused MLP: TM=64, 16 waves, wave owns 64 cols; Phase B = 32x32x16 MFMA,
// ---------------- B from fragment-packed W2P, prefetch depth 3, fully unrolled t-loop ----------------
__global__ __launch_bounds__(1024, 4) void mlp_fused(const u16* __restrict__ xt2b,   // [100032][32]
                                                     const u16* __restrict__ W1T,    // [1024][32]
                                                     const float* __restrict__ bm1,
                                                     const u16* __restrict__ W2P,    // packed, 2 MB
                                                     const float* __restrict__ bm2,
                                                     const u16* __restrict__ W3T,    // [16][1024]
                                                     const float* __restrict__ bm3,
                                                     float* __restrict__ probs,
                                                     float* __restrict__ logitsO) {
    __shared__ __align__(16) u16 h1s[TM * HP1];        // 132096 B (reused as f32 reduce buf)
    __shared__ __align__(16) u16 scr[16 * 16 * SCP2];  // 18432 B per-wave phase-C scratch
    const int tid = threadIdx.x;
    const int w = tid >> 6;          // 0..15
    const int lane = tid & 63;
    const int l16 = lane & 15;
    const int q = lane >> 4;
    const int m32 = lane & 31;       // 32x32 row/col index
    const int h8 = (lane >> 5) * 8;  // 32x32 k-offset
    const int row0 = blockIdx.x * TM;
    const int nb0 = w * 64;

    // per-wave packed-B stream base: chunk (t,j) at wq + (t*2+j)*512
    const u16* wq = W2P + (size_t)w * 128 * 512 + (size_t)lane * 8;

    // ---- B pipeline preload (t=0,1,2) — issued before Phase A to hide latency
    bf16x8 bp[3][2];
#pragma unroll
    for (int s = 0; s < 3; ++s)
#pragma unroll
        for (int j = 0; j < 2; ++j)
            bp[s][j] = *(const bf16x8*)(wq + (s * 2 + j) * 512);

    // ---- Phase A: h1 rows [row0,row0+64) = relu(xt2 @ Wm1 + bm1) -> LDS (wave fills its 64 cols)
#pragma unroll
    for (int mt = 0; mt < 4; ++mt) {
        const int grow = row0 + mt * 16 + l16;               // < 100032 (1563*64)
        bf16x8 a = *(const bf16x8*)(xt2b + grow * 32 + q * 8);
#pragma unroll
        for (int nt = 0; nt < 4; ++nt) {
            const int n = nb0 + nt * 16 + l16;
            bf16x8 b = *(const bf16x8*)(W1T + n * 32 + q * 8);
            f32x4 c = {0.f, 0.f, 0.f, 0.f};
            c = __builtin_amdgcn_mfma_f32_16x16x32_bf16(a, b, c, 0, 0, 0);
            const float bias = bm1[n];
#pragma unroll
            for (int r = 0; r < 4; ++r)
                h1s[(mt * 16 + q * 4 + r) * HP1 + n] = f2bf(fmaxf(c[r] + bias, 0.f));
        }
    }
    __syncthreads();

    // ---- Phase B: 64 k-steps of 16; wave computes 2x2 32x32 tiles; fully unrolled, depth-3 B pipe
    f32x16 acc[2][2];
#pragma unroll
    for (int i2 = 0; i2 < 2; ++i2)
#pragma unroll
        for (int j = 0; j < 2; ++j)
#pragma unroll
            for (int r = 0; r < 16; ++r) acc[i2][j][r] = 0.f;

#pragma unroll
    for (int t = 0; t < 64; ++t) {
        const int s = t % 3;
        const int k0 = t * 16;
        bf16x8 a0 = *(const bf16x8*)(h1s + (0 * 32 + m32) * HP1 + k0 + h8);
        bf16x8 a1 = *(const bf16x8*)(h1s + (1 * 32 + m32) * HP1 + k0 + h8);
        acc[0][0] = __builtin_amdgcn_mfma_f32_32x32x16_bf16(a0, bp[s][0], acc[0][0], 0, 0, 0);
        acc[1][0] = __builtin_amdgcn_mfma_f32_32x32x16_bf16(a1, bp[s][0], acc[1][0], 0, 0, 0);
        acc[0][1] = __builtin_amdgcn_mfma_f32_32x32x16_bf16(a0, bp[s][1], acc[0][1], 0, 0, 0);
        acc[1][1] = __builtin_amdgcn_mfma_f32_32x32x16_bf16(a1, bp[s][1], acc[1][1], 0, 0, 0);
        if (t + 3 < 64) {
            bp[s][0] = *(const bf16x8*)(wq + ((t + 3) * 2 + 0) * 512);
            bp[s][1] = *(const bf16x8*)(wq + ((t + 3) * 2 + 1) * 512);
        }
    }

    // ---- epilogue + Phase C: per 16x32 chunk -> scratch (A-layout) -> logits MFMA
    const float bias2[2] = { bm2[nb0 + m32], bm2[nb0 + 32 + m32] };
    f32x4 plog[4];
#pragma unroll
    for (int mt = 0; mt < 4; ++mt) plog[mt] = (f32x4){0.f, 0.f, 0.f, 0.f};
    u16* sw = scr + w * 16 * SCP2;

#pragma unroll
    for (int i2 = 0; i2 < 2; ++i2)
#pragma unroll
        for (int rh = 0; rh < 2; ++rh) {
            const int mt = i2 * 2 + rh;
#pragma unroll
            for (int j = 0; j < 2; ++j) {
#pragma unroll
                for (int rr = 0; rr < 8; ++rr) {
                    // 32x32 C-layout: row=(reg&3)+8*(reg>>2)+4*(lane>>5), col=lane&31
                    const int row16 = (rr & 3) + 8 * (rr >> 2) + 4 * (lane >> 5);
                    float v = acc[i2][j][rh * 8 + rr] + bias2[j];
                    sw[row16 * SCP2 + m32] = f2bf(fmaxf(v, 0.f));
                }
                bf16x8 a2 = *(const bf16x8*)(sw + l16 * SCP2 + q * 8);
                bf16x8 b3 = *(const bf16x8*)(W3T + l16 * 1024 + nb0 + j * 32 + q * 8);
                plog[mt] = __builtin_amdgcn_mfma_f32_16x16x32_bf16(a2, b3, plog[mt], 0, 0, 0);
            }
        }

    // ---- cross-wave logit reduction (reuse h1s as f32 buffer: 16*4*64*16B = 64 KB)
    __syncthreads();
    f32x4* red = (f32x4*)h1s;
#pragma unroll
    for (int mt = 0; mt < 4; ++mt) red[(w * 4 + mt) * 64 + lane] = plog[mt];
    __syncthreads();

    if (w < 4) {                                   // wave w finalizes m-tile w
        f32x4 tot = red[w * 64 + lane];
#pragma unroll
        for (int w2 = 1; w2 < 16; ++w2) tot = tot + red[(w2 * 4 + w) * 64 + lane];
        const float b3v = bm3[l16];
#pragma unroll
        for (int r = 0; r < 4; ++r) {
            float v = tot[r] + b3v;
            float m = v;
            m = fmaxf(m, __shfl_xor(m, 1));
            m = fmaxf(m, __shfl_xor(m, 2));
            m = fmaxf(m, __shfl_xor(m, 4));
            m = fmaxf(m, __shfl_xor(m, 8));
            float e = __expf(v - m);
            float s = e;
            s += __shfl_xor(s, 1);
            s += __shfl_xor(s, 2);
            s += __shfl_xor(s, 4);
            s += __shfl_xor(s, 8);
            const int R = row0 + w * 16 + q * 4 + r;
            if (R < N_NODES) {
                logitsO[R * 16 + l16] = v;
                probs[R * 16 + l16] = e / s;
            }
        }
    }
}

extern "C" void kernel_launch(void* const* d_in, const int* in_sizes, int n_in,
                              void* d_out, int out_size, void* d_ws, size_t ws_size,
                              hipStream_t stream) {
    const float* x   = (const float*)d_in[0];
    const int*   ei  = (const int*)d_in[1];
    const int*   src = ei;
    const int*   dst = ei + N_EDGES;
    const float* W1l = (const float*)d_in[2];
    const float* b1l = (const float*)d_in[3];
    const float* W1r = (const float*)d_in[4];
    const float* g1  = (const float*)d_in[5];
    const float* be1 = (const float*)d_in[6];
    const float* W2l = (const float*)d_in[7];
    const float* b2l = (const float*)d_in[8];
    const float* W2r = (const float*)d_in[9];
    const float* g2  = (const float*)d_in[10];
    const float* be2 = (const float*)d_in[11];
    const float* Wm1 = (const float*)d_in[12];
    const float* bm1 = (const float*)d_in[13];
    const float* Wm2 = (const float*)d_in[14];
    const float* bm2 = (const float*)d_in[15];
    const float* Wm3 = (const float*)d_in[16];
    const float* bm3 = (const float*)d_in[17];

    float* probs  = (float*)d_out;                 // [N,16]
    float* logits = probs + 1600000;               // [N,16]
    float* xt1    = probs + 3200000;               // [N,64]
    float* xt2    = probs + 9600000;               // [N,32]

    char* wsb    = (char*)d_ws;
    int*  deg    = (int*)(wsb);                    //   400,000 B
    float* stats = (float*)(wsb + 400000);         //       768 B
    int*  offs   = (int*)(wsb + 400768);           //   400,000 B
    int*  eidx   = (int*)(wsb + 800768);           // 6,400,000 B
    float* mean  = (float*)(wsb + 7200768);        // 25,600,000 B
    int*  bsum   = (int*)(wsb + 7200768);          // overlaps mean (dead until agg_mean)
    u16*  xt2b   = (u16*)(wsb + 32800768);         // 6,402,048 B ([100032][32])
    u16*  W1T    = (u16*)(wsb + 39202816);         //    65,536 B
    u16*  W2P    = (u16*)(wsb + 39268352);         // 2,097,152 B (fragment-packed Wm2)
    u16*  W3T    = (u16*)(wsb + 41365504);         //    32,768 B  (end: 41,398,272)
    float* sum1 = stats, *sq1 = stats + 64, *sum2 = stats + 128, *sq2 = stats + 160;

    // zero deg + stats; zero xt2b tail rows 100000..100031
    hipMemsetAsync(wsb, 0, 400768, stream);
    hipMemsetAsync(xt2b + 100000 * 32, 0, 32 * 32 * sizeof(u16), stream);

    // weight transforms (bf16)
    transpose_cvt<<<dim3(32, 1),  dim3(32, 8), 0, stream>>>(Wm1, W1T, 32, 1024);
    pack_w2<<<512, 256, 0, stream>>>(Wm2, W2P);
    transpose_cvt<<<dim3(1, 32),  dim3(32, 8), 0, stream>>>(Wm3, W3T, 1024, 16);

    // ---- CSR build (once; reused by both layers)
    hist_deg<<<6250, 256, 0, stream>>>(dst, deg, N_EDGES);
    scan_blk<<<98, 1024, 0, stream>>>(deg, offs, bsum, N_NODES);
    scan_top<<<1, 64, 0, stream>>>(bsum, 98);
    scan_add<<<98, 1024, 0, stream>>>(offs, bsum, N_NODES);
    fill_csr<<<6250, 256, 0, stream>>>(src, dst, offs, eidx, N_EDGES);

    // ---- layer 1
    agg_mean<<<6250, 256, 0, stream>>>((const f32x4*)x, offs, deg, eidx, (f32x4*)mean, N_NODES);
    sage_gemm<64><<<512, 256, 0, stream>>>((const f32x4*)mean, (const f32x4*)x,
                                           W1l, W1r, b1l, xt1, sum1, sq1, N_NODES);
    bn_relu<64, 0><<<4096, 256, 0, stream>>>(xt1, sum1, sq1, g1, be1, nullptr, N_NODES);

    // ---- layer 2
    agg_mean<<<6250, 256, 0, stream>>>((const f32x4*)xt1, offs, deg, eidx, (f32x4*)mean, N_NODES);
    sage_gemm<32><<<512, 256, 0, stream>>>((const f32x4*)mean, (const f32x4*)xt1,
                                           W2l, W2r, b2l, xt2, sum2, sq2, N_NODES);
    bn_relu<32, 1><<<2048, 256, 0, stream>>>(xt2, sum2, sq2, g2, be2, xt2b, N_NODES);

    // ---- fused MLP + softmax
    mlp_fused<<<1563, 1024, 0, stream>>>(xt2b, W1T, bm1, W2P, bm2, W3T, bm3, probs, logits);
}